// Round 6
// baseline (1797.841 us; speedup 1.0000x reference)
//
#include <hip/hip_runtime.h>
#include <stdint.h>

// Problem dims (fixed): T=256, B=128, I=512, H=1024, O=1
typedef __attribute__((ext_vector_type(8))) short short8;
typedef __attribute__((ext_vector_type(4))) float f32x4;
typedef __attribute__((ext_vector_type(4))) unsigned int u32x4;

__device__ __forceinline__ unsigned short f2bf(float f) {
  unsigned u = __float_as_uint(f);
  u += 0x7FFFu + ((u >> 16) & 1u);   // RNE
  return (unsigned short)(u >> 16);
}
__device__ __forceinline__ float bf2f(unsigned short s) {
  return __uint_as_float(((unsigned)s) << 16);
}
__device__ __forceinline__ float ftanh(float x) {
  float e = __expf(2.0f * x);
  return 1.0f - 2.0f / (e + 1.0f);
}

// ---------------- fp32 -> bf16 convert (vectorized, 8 elem/thread) ----------
__global__ __launch_bounds__(256) void cvt_kernel(const float* __restrict__ in,
                                                  unsigned short* __restrict__ out,
                                                  int n8) {
  int i = blockIdx.x * 256 + threadIdx.x;
  if (i >= n8) return;
  const float4* p = (const float4*)in + (size_t)i * 2;
  float4 a = p[0], b = p[1];
  uint4 o;
  o.x = (unsigned)f2bf(a.x) | ((unsigned)f2bf(a.y) << 16);
  o.y = (unsigned)f2bf(a.z) | ((unsigned)f2bf(a.w) << 16);
  o.z = (unsigned)f2bf(b.x) | ((unsigned)f2bf(b.y) << 16);
  o.w = (unsigned)f2bf(b.z) | ((unsigned)f2bf(b.w) << 16);
  ((uint4*)out)[i] = o;
}

// ---------------- xp GEMM: xp[m][n] = sum_k x[m][k]*W_ih[n][k] + b_ih[n]+b_hh[n]
__global__ __launch_bounds__(256) void gemm_xp(const unsigned short* __restrict__ A,
                                               const unsigned short* __restrict__ Bw,
                                               const float* __restrict__ b_ih,
                                               const float* __restrict__ b_hh,
                                               unsigned short* __restrict__ xp) {
  __shared__ unsigned short Al[8192];
  __shared__ unsigned short Bl[8192];
  int tid = threadIdx.x, lane = tid & 63, w = tid >> 6;
  int wm = w & 1, wn = w >> 1;
  int bx = blockIdx.x;
  int m0 = (bx >> 3) * 128, n0 = (bx & 7) * 128;

  f32x4 acc[4][4];
#pragma unroll
  for (int i = 0; i < 4; ++i)
#pragma unroll
    for (int jq = 0; jq < 4; ++jq) acc[i][jq] = (f32x4){0.f, 0.f, 0.f, 0.f};

  for (int kb = 0; kb < 512; kb += 64) {
#pragma unroll
    for (int i = 0; i < 4; ++i) {
      int S = (w * 4 + i) * 64 + lane;
      int row = S >> 3, pg = S & 7;
      int gk = ((pg ^ (row & 7)) << 3);
      const unsigned short* ga = A + (size_t)(m0 + row) * 512 + kb + gk;
      const unsigned short* gb = Bw + (size_t)(n0 + row) * 512 + kb + gk;
      __builtin_amdgcn_global_load_lds(
          (const __attribute__((address_space(1))) unsigned int*)ga,
          (__attribute__((address_space(3))) unsigned int*)&Al[(size_t)((w * 4 + i) * 64) * 8],
          16, 0, 0);
      __builtin_amdgcn_global_load_lds(
          (const __attribute__((address_space(1))) unsigned int*)gb,
          (__attribute__((address_space(3))) unsigned int*)&Bl[(size_t)((w * 4 + i) * 64) * 8],
          16, 0, 0);
    }
    asm volatile("s_waitcnt vmcnt(0)" ::: "memory");
    __syncthreads();

#pragma unroll
    for (int c = 0; c < 2; ++c) {
      short8 av[4], bv[4];
      int gg = c * 4 + (lane >> 4);
#pragma unroll
      for (int mt = 0; mt < 4; ++mt) {
        int rowa = wm * 64 + mt * 16 + (lane & 15);
        av[mt] = *(const short8*)&Al[(rowa * 8 + (gg ^ (rowa & 7))) * 8];
        int rowb = wn * 64 + mt * 16 + (lane & 15);
        bv[mt] = *(const short8*)&Bl[(rowb * 8 + (gg ^ (rowb & 7))) * 8];
      }
#pragma unroll
      for (int mt = 0; mt < 4; ++mt)
#pragma unroll
        for (int nt = 0; nt < 4; ++nt)
          acc[mt][nt] = __builtin_amdgcn_mfma_f32_16x16x32_bf16(av[mt], bv[nt], acc[mt][nt], 0, 0, 0);
    }
    __syncthreads();
  }

  int cl = lane & 15, qd = lane >> 4;
#pragma unroll
  for (int nt = 0; nt < 4; ++nt) {
    int col = n0 + wn * 64 + nt * 16 + cl;
    float bias = b_ih[col] + b_hh[col];
#pragma unroll
    for (int mt = 0; mt < 4; ++mt) {
#pragma unroll
      for (int r = 0; r < 4; ++r) {
        int m = m0 + wm * 64 + mt * 16 + qd * 4 + r;
        xp[(size_t)m * 1024 + col] = f2bf(acc[mt][nt][r] + bias);
      }
    }
  }
}

// ---------------- the scan (barrier-free async waves) -----------------------
// 128 WGs x 256 thr (4 waves), 1 WG/CU. group g = blk&7 (16 batches,
// XCD-local heuristic), producer p = blk>>3 owns cols [p*64,p*64+64);
// wave w owns the 16x16 tile at p*64+w*16. Each WAVE is an independent
// agent: per step it (a) polls one coalesced 256-B tag block (4 B/lane,
// exact-match ==s-1; reuse-safe by backpressure: tag slot (s-1)&1 can only
// be overwritten at step s+1, which requires every wave to have passed this
// poll), (b) bulk-loads h[s-1] A-frags DIRECTLY from per-step-disjoint hs
// with plain cached loads (lines untouched pre-publish -> never stale;
// same-XCD waves share L2 fills), (c) MFMA with W_hh B-frags resident in
// AGPRs, (d) tanh, (e) publishes its tile via sc0 sc1 b16 stores, one
// vmcnt(0) ack, then its own tag word. NO __syncthreads in the loop, no LDS.
__global__ __launch_bounds__(256, 1) void scan_kernel(
    const float* __restrict__ Whh, const unsigned short* __restrict__ xp,
    char* __restrict__ hsb, unsigned* __restrict__ tags) {
  const int tid = threadIdx.x;
  const int lane = tid & 63, w = tid >> 6;
  const int g = blockIdx.x & 7, p = blockIdx.x >> 3;   // g: XCD-local groups
  const int r = lane & 15, q = lane >> 4;
  const int b0 = g * 16;
  const int gcol = p * 64 + w * 16 + r;   // this lane's output column
  const int myid = p * 4 + w;             // producer-wave id 0..63

  // ---- W_hh -> B-frags (AGPR-resident): lane (r,q) holds W[gcol][c*32+q*8..+7]
  short8 Bfrag[32];
  {
    const float* wsrc = Whh + (size_t)gcol * 1024 + q * 8;
#pragma unroll
    for (int c = 0; c < 32; ++c) {
      float4 v0 = *(const float4*)(wsrc + c * 32);
      float4 v1 = *(const float4*)(wsrc + c * 32 + 4);
      short8 sv;
      sv[0] = (short)f2bf(v0.x); sv[1] = (short)f2bf(v0.y);
      sv[2] = (short)f2bf(v0.z); sv[3] = (short)f2bf(v0.w);
      sv[4] = (short)f2bf(v1.x); sv[5] = (short)f2bf(v1.y);
      sv[6] = (short)f2bf(v1.z); sv[7] = (short)f2bf(v1.w);
      Bfrag[c] = sv;
    }
  }

  // xp for s=1
  float xpv[4];
#pragma unroll
  for (int rr = 0; rr < 4; ++rr)
    xpv[rr] = bf2f(xp[((size_t)1 * 128 + b0 + q * 4 + rr) * 1024 + gcol]);

  for (int s = 1; s < 256; ++s) {
    short8 hv[32];
    if (s == 1) {
      // ---- h0 A-frags computed locally from xp[0] (no publish, no sync)
#pragma unroll
      for (int c = 0; c < 32; ++c) {
        u32x4 xv = *(const u32x4*)(xp + (size_t)(b0 + r) * 1024 + c * 32 + q * 8);
        const unsigned short* xs = (const unsigned short*)&xv;
        short8 sv;
#pragma unroll
        for (int jj = 0; jj < 8; ++jj) sv[jj] = (short)f2bf(ftanh(bf2f(xs[jj])));
        hv[c] = sv;
      }
    } else {
      // ---- poll this group's 64 tag words: lane l checks producer-wave l.
      {
        const unsigned* ta = tags + (size_t)(((s - 1) & 1) * 8 + g) * 64 + lane;
        int guard = 0;
        while (true) {
          int tv;
          asm volatile("global_load_dword %0, %1, off sc0 sc1\n\ts_waitcnt vmcnt(0)"
                       : "=v"(tv)
                       : "v"((unsigned long long)(uintptr_t)ta)
                       : "memory");
          if (__all(tv == s - 1)) break;
          if (++guard > (1 << 20)) break;  // fail-safe: terminate (fails check)
        }
      }
      // ---- bulk-load h[s-1] A-frags (plain cached; L2-shared across waves)
      const unsigned short* hbase =
          (const unsigned short*)(hsb + (size_t)(s - 1) * 262144) + (size_t)(b0 + r) * 1024 + q * 8;
#pragma unroll
      for (int c = 0; c < 32; ++c)
        hv[c] = __builtin_bit_cast(short8, *(const u32x4*)(hbase + c * 32));
    }

    // ---- MFMA: 16x16 tile over K=1024, 4 independent chains
    f32x4 acc[4];
#pragma unroll
    for (int i = 0; i < 4; ++i) acc[i] = (f32x4){0.f, 0.f, 0.f, 0.f};
#pragma unroll
    for (int c = 0; c < 32; ++c)
      acc[c & 3] = __builtin_amdgcn_mfma_f32_16x16x32_bf16(hv[c], Bfrag[c], acc[c & 3], 0, 0, 0);

    // ---- h = tanh(acc + xp); publish tile (b16 sc0 sc1 stores)
    char* hout = hsb + (size_t)s * 262144;
#pragma unroll
    for (int rr = 0; rr < 4; ++rr) {
      float h = ftanh(acc[0][rr] + acc[1][rr] + acc[2][rr] + acc[3][rr] + xpv[rr]);
      unsigned hb = (unsigned)f2bf(h);
      unsigned long long addr = (unsigned long long)(uintptr_t)(
          hout + ((size_t)(b0 + q * 4 + rr) * 1024 + gcol) * 2);
      asm volatile("global_store_short %0, %1, off sc0 sc1"
                   :: "v"(addr), "v"(hb) : "memory");
    }
    asm volatile("s_waitcnt vmcnt(0)" ::: "memory");  // publish acked at coherence pt
    if (lane == 0) {
      unsigned* ta = tags + (size_t)((s & 1) * 8 + g) * 64 + myid;
      asm volatile("global_store_dword %0, %1, off sc0 sc1"
                   :: "v"((unsigned long long)(uintptr_t)ta), "v"(s) : "memory");
    }

    // ---- xp prefetch for s+1 (plain; completes under next poll)
    int sn = (s < 255) ? s + 1 : 255;
#pragma unroll
    for (int rr = 0; rr < 4; ++rr)
      xpv[rr] = bf2f(xp[((size_t)sn * 128 + b0 + q * 4 + rr) * 1024 + gcol]);
  }
}

// ---------------- head GEMV: out[t*128+b] = dot(h[t,b,:], W_fc) + b_fc ------
// t>=1 rows come from hs; t==0 row is tanh(xp[0]) computed on the fly.
__global__ __launch_bounds__(256) void head_gemv(const char* __restrict__ hsb,
                                                 const unsigned short* __restrict__ xp,
                                                 const float* __restrict__ Wfc,
                                                 const float* __restrict__ bfc,
                                                 float* __restrict__ out) {
  int gtid = blockIdx.x * 256 + threadIdx.x;
  int wv = gtid >> 6, l = gtid & 63;
  int t = wv >> 7, b = wv & 127;
  const unsigned short* row =
      (t == 0) ? (xp + (size_t)b * 1024 + l * 16)
               : ((const unsigned short*)(hsb + (size_t)t * 262144) + (size_t)b * 1024 + l * 16);
  float v[16];
#pragma unroll
  for (int i = 0; i < 16; ++i) v[i] = bf2f(row[i]);
  if (t == 0) {
#pragma unroll
    for (int i = 0; i < 16; ++i) v[i] = ftanh(v[i]);
  }
  const float4* wf = (const float4*)(Wfc + l * 16);
  float acc = 0.f;
#pragma unroll
  for (int i = 0; i < 4; ++i) {
    float4 wq = wf[i];
    acc += v[4 * i] * wq.x + v[4 * i + 1] * wq.y + v[4 * i + 2] * wq.z + v[4 * i + 3] * wq.w;
  }
#pragma unroll
  for (int off = 32; off; off >>= 1) acc += __shfl_down(acc, off, 64);
  if (l == 0) out[wv] = acc + bfc[0];
}

// ---------------- launcher --------------------------------------------------
extern "C" void kernel_launch(void* const* d_in, const int* in_sizes, int n_in,
                              void* d_out, int out_size, void* d_ws, size_t ws_size,
                              hipStream_t stream) {
  (void)in_sizes; (void)n_in; (void)out_size; (void)ws_size;
  const float* x   = (const float*)d_in[0];
  const float* Wih = (const float*)d_in[1];
  const float* Whh = (const float*)d_in[2];
  const float* bih = (const float*)d_in[3];
  const float* bhh = (const float*)d_in[4];
  const float* Wfc = (const float*)d_in[5];
  const float* bfc = (const float*)d_in[6];
  float* out = (float*)d_out;

  char* ws = (char*)d_ws;
  // Workspace = EXACTLY 128 MiB (r1-proven available):
  //   0..64M   : xp (bf16, gemm output, live for whole scan)
  //   64M..128M: hs[0..255], 256 KB/step. hs[0] is NEVER published (h0 is
  //              computed locally) -> its slot hosts the 4 KB tag array.
  //              xb (32 MB) aliases hs[1..128]; wb (1 MB) aliases hs[129..132]
  //              — both dead after gemm_xp, before scan publishes there.
  unsigned short* xp = (unsigned short*)(ws);
  char* hsb          = ws + 67108864;
  unsigned* tags     = (unsigned*)(hsb);                 // hs[0] slot (4 KB used)
  unsigned short* xb = (unsigned short*)(hsb + 262144);  // hs[1..128]
  unsigned short* wb = (unsigned short*)(hsb + 262144 + 33554432);  // hs[129..132]

  // tags need NO init: poll is exact-match (tag==s, s in 1..255; 0xAA poison
  // never matches). out is fully overwritten by head_gemv. No memsets.

  cvt_kernel<<<8192, 256, 0, stream>>>(x, xb, 2097152);     // x fp32 -> bf16
  cvt_kernel<<<256, 256, 0, stream>>>(Wih, wb, 65536);      // W_ih fp32 -> bf16
  gemm_xp<<<2048, 256, 0, stream>>>(xb, wb, bih, bhh, xp);  // xp = x@W_ih^T + b
  scan_kernel<<<128, 256, 0, stream>>>(Whh, xp, hsb, tags); // 256-step recurrence
  head_gemv<<<8192, 256, 0, stream>>>(hsb, xp, Wfc, bfc, out);
}